// Round 1
// baseline (76.726 us; speedup 1.0000x reference)
//
#include <hip/hip_runtime.h>
#include <hip/hip_bf16.h>

#define N_ROWS 8192
#define K_CENT 128
#define D_DIM  512

typedef short v8s __attribute__((ext_vector_type(8)));
typedef float v4f __attribute__((ext_vector_type(4)));

// fp32 -> bf16 round-to-nearest-even (bit trick; inputs are finite normals)
__device__ inline unsigned short f2bf(float f) {
    union { float f; unsigned u; } v; v.f = f;
    unsigned r = v.u + 0x7FFFu + ((v.u >> 16) & 1u);
    return (unsigned short)(r >> 16);
}

// One wave per centroid row: compute ||c_k||^2 (fp32) and bf16 copy of c.
__global__ __launch_bounds__(256) void prep_centroids(const float* __restrict__ c,
                                                      float* __restrict__ cnorm,
                                                      unsigned short* __restrict__ cb) {
    int wave = (int)((blockIdx.x * blockDim.x + threadIdx.x) >> 6);
    int lane = threadIdx.x & 63;
    if (wave >= K_CENT) return;
    const float* src = c + (size_t)wave * D_DIM;
    float4 a = ((const float4*)src)[lane];        // dims 4*lane .. +3   (0..255)
    float4 b = ((const float4*)src)[64 + lane];   // dims 256+4*lane .. (256..511)
    float s = a.x*a.x + a.y*a.y + a.z*a.z + a.w*a.w
            + b.x*b.x + b.y*b.y + b.z*b.z + b.w*b.w;
    #pragma unroll
    for (int off = 32; off >= 1; off >>= 1) s += __shfl_xor(s, off, 64);
    if (lane == 0) cnorm[wave] = s;
    unsigned short* dst = cb + (size_t)wave * D_DIM;
    ushort4 p0, p1;
    p0.x = f2bf(a.x); p0.y = f2bf(a.y); p0.z = f2bf(a.z); p0.w = f2bf(a.w);
    p1.x = f2bf(b.x); p1.y = f2bf(b.y); p1.z = f2bf(b.z); p1.w = f2bf(b.w);
    ((ushort4*)dst)[lane]      = p0;
    ((ushort4*)dst)[64 + lane] = p1;
}

// One wave per 16 x-rows; computes all 128 centroid distances for those rows.
// A-frag: x[m=lane&15][k = quad*8 + j]  (contiguous 8 floats, converted to bf16)
// B-frag: c[n=lane&15 + 16g][k = quad*8 + j] (contiguous 8 bf16 from ws copy)
// D-frag: D[m = quad*4 + reg][n = lane&15]  (verified gfx950 16x16x32 layout)
__global__ __launch_bounds__(64) void dist_kernel(const float* __restrict__ x,
                                                  const unsigned short* __restrict__ cb,
                                                  const float* __restrict__ cnorm,
                                                  float* __restrict__ out) {
    const int lane = threadIdx.x;
    const int n16  = lane & 15;
    const int quad = lane >> 4;
    const int rowbase = blockIdx.x * 16;

    const float* xptr = x + (size_t)(rowbase + n16) * D_DIM + quad * 8;
    const unsigned short* bptr = cb + (size_t)n16 * D_DIM + quad * 8;

    v4f acc[8];
    #pragma unroll
    for (int g = 0; g < 8; ++g) acc[g] = (v4f){0.f, 0.f, 0.f, 0.f};

    float sn = 0.f;  // partial ||x_row||^2 over this lane's k slots

    for (int kk = 0; kk < D_DIM; kk += 32) {
        float4 a0 = *(const float4*)(xptr);
        float4 a1 = *(const float4*)(xptr + 4);
        sn += a0.x*a0.x + a0.y*a0.y + a0.z*a0.z + a0.w*a0.w
            + a1.x*a1.x + a1.y*a1.y + a1.z*a1.z + a1.w*a1.w;
        v8s afrag;
        afrag[0] = (short)f2bf(a0.x); afrag[1] = (short)f2bf(a0.y);
        afrag[2] = (short)f2bf(a0.z); afrag[3] = (short)f2bf(a0.w);
        afrag[4] = (short)f2bf(a1.x); afrag[5] = (short)f2bf(a1.y);
        afrag[6] = (short)f2bf(a1.z); afrag[7] = (short)f2bf(a1.w);
        #pragma unroll
        for (int g = 0; g < 8; ++g) {
            v8s bfrag = *(const v8s*)(bptr + (size_t)g * 16 * D_DIM);
            acc[g] = __builtin_amdgcn_mfma_f32_16x16x32_bf16(afrag, bfrag, acc[g], 0, 0, 0);
        }
        xptr += 32;
        bptr += 32;
    }

    // lanes {n16, n16+16, n16+32, n16+48} together hold the full row sum
    sn += __shfl_xor(sn, 16, 64);
    sn += __shfl_xor(sn, 32, 64);
    // lane l (l<16 suffices) now holds ||x[rowbase + (l&15)]||^2

    float xn[4];
    #pragma unroll
    for (int r = 0; r < 4; ++r) xn[r] = __shfl(sn, quad * 4 + r, 64);

    #pragma unroll
    for (int g = 0; g < 8; ++g) {
        float cn = cnorm[g * 16 + n16];
        #pragma unroll
        for (int r = 0; r < 4; ++r) {
            float d2 = xn[r] + cn - 2.0f * acc[g][r];
            d2 = d2 > 0.f ? d2 : 0.f;
            out[(size_t)(rowbase + quad * 4 + r) * K_CENT + g * 16 + n16] = sqrtf(d2);
        }
    }
}

// Correctness fallback if ws is unexpectedly tiny: one thread per output.
__global__ void naive_kernel(const float* __restrict__ x, const float* __restrict__ c,
                             float* __restrict__ out) {
    int idx = blockIdx.x * blockDim.x + threadIdx.x;
    if (idx >= N_ROWS * K_CENT) return;
    int n = idx / K_CENT, k = idx % K_CENT;
    const float* xr = x + (size_t)n * D_DIM;
    const float* cr = c + (size_t)k * D_DIM;
    float s = 0.f;
    for (int d = 0; d < D_DIM; ++d) { float df = xr[d] - cr[d]; s += df * df; }
    out[idx] = sqrtf(s);
}

extern "C" void kernel_launch(void* const* d_in, const int* in_sizes, int n_in,
                              void* d_out, int out_size, void* d_ws, size_t ws_size,
                              hipStream_t stream) {
    const float* x = (const float*)d_in[0];
    const float* c = (const float*)d_in[1];
    float* out = (float*)d_out;

    const size_t need = 512 + (size_t)K_CENT * D_DIM * sizeof(unsigned short); // cnorm + bf16 c
    if (ws_size < need) {
        int total = N_ROWS * K_CENT;
        naive_kernel<<<(total + 255) / 256, 256, 0, stream>>>(x, c, out);
        return;
    }

    float* cnorm = (float*)d_ws;
    unsigned short* cb = (unsigned short*)((char*)d_ws + 512);

    prep_centroids<<<(K_CENT * 64 + 255) / 256, 256, 0, stream>>>(c, cnorm, cb);
    dist_kernel<<<N_ROWS / 16, 64, 0, stream>>>(x, cb, cnorm, out);
}